// Round 2
// baseline (916.595 us; speedup 1.0000x reference)
//
#include <hip/hip_runtime.h>
#include <cstdint>
#include <cstddef>

// Problem constants
#define B_   4
#define L_   512
#define DIM_ 1024
#define H_   8
#define DQK_ 64
#define DV_  64
#define M_   (B_ * L_)          // 2048 rows
#define EPS_ 1e-5f

// ---------------------------------------------------------------------------
// Tiled fp32 GEMM: C[M,N] = A[M,K] @ W[N,K]^T + bias[N]
// BM=BN=64, BK=16, 256 threads, 4x4 micro-tile per thread.
// ---------------------------------------------------------------------------
constexpr int BM = 64, BN = 64, BKk = 16;

__global__ __launch_bounds__(256) void gemm_bias(
    const float* __restrict__ A, const float* __restrict__ W,
    const float* __restrict__ bias, float* __restrict__ C,
    int M, int N, int K)
{
    __shared__ float As[BKk][BM + 4];
    __shared__ float Bs[BKk][BN + 4];

    const int t  = threadIdx.x;
    const int bm = blockIdx.y * BM;
    const int bn = blockIdx.x * BN;
    const int tm = (t >> 4) << 2;
    const int tn = (t & 15) << 2;
    const int lr = t >> 2;
    const int lk = (t & 3) << 2;

    float acc[4][4] = {};

    const float* Arow = A + (size_t)(bm + lr) * K + lk;
    const float* Wrow = W + (size_t)(bn + lr) * K + lk;

    for (int k0 = 0; k0 < K; k0 += BKk) {
        float4 av = *(const float4*)(Arow + k0);
        float4 wv = *(const float4*)(Wrow + k0);
        As[lk + 0][lr] = av.x; As[lk + 1][lr] = av.y;
        As[lk + 2][lr] = av.z; As[lk + 3][lr] = av.w;
        Bs[lk + 0][lr] = wv.x; Bs[lk + 1][lr] = wv.y;
        Bs[lk + 2][lr] = wv.z; Bs[lk + 3][lr] = wv.w;
        __syncthreads();
#pragma unroll
        for (int kk = 0; kk < BKk; ++kk) {
            float4 a = *(const float4*)&As[kk][tm];
            float4 b = *(const float4*)&Bs[kk][tn];
            float av4[4] = {a.x, a.y, a.z, a.w};
            float bv4[4] = {b.x, b.y, b.z, b.w};
#pragma unroll
            for (int i2 = 0; i2 < 4; ++i2)
#pragma unroll
                for (int j2 = 0; j2 < 4; ++j2)
                    acc[i2][j2] = fmaf(av4[i2], bv4[j2], acc[i2][j2]);
        }
        __syncthreads();
    }

    float4 bv;
    bv.x = bias[bn + tn + 0]; bv.y = bias[bn + tn + 1];
    bv.z = bias[bn + tn + 2]; bv.w = bias[bn + tn + 3];
#pragma unroll
    for (int i2 = 0; i2 < 4; ++i2) {
        float4 o;
        o.x = acc[i2][0] + bv.x; o.y = acc[i2][1] + bv.y;
        o.z = acc[i2][2] + bv.z; o.w = acc[i2][3] + bv.w;
        *(float4*)(C + (size_t)(bm + tm + i2) * N + bn + tn) = o;
    }
}

// ---------------------------------------------------------------------------
// Small GEMM for a_angle: out[M_,H_] = x @ w_a^T + b_a.  One wave per output.
// ---------------------------------------------------------------------------
__global__ __launch_bounds__(256) void gemm_a_kernel(
    const float* __restrict__ x, const float* __restrict__ wa,
    const float* __restrict__ ba, float* __restrict__ out)
{
    const int w    = threadIdx.x >> 6;
    const int lane = threadIdx.x & 63;
    const int oidx = blockIdx.x * 4 + w;
    const int r = oidx >> 3, h = oidx & 7;
    const float* xr = x + (size_t)r * DIM_;
    const float* wr = wa + (size_t)h * DIM_;
    float p = 0.f;
    for (int k = lane; k < DIM_; k += 64)
        p = fmaf(xr[k], wr[k], p);
#pragma unroll
    for (int off = 32; off; off >>= 1)
        p += __shfl_down(p, off);
    if (lane == 0) out[oidx] = p + ba[h];
}

// ---------------------------------------------------------------------------
// Phase kernel: in-place transform qk proj -> (qp, kp); also compute lam.
// qk layout per (b,l,h,i): [q_re, q_im, k_re, k_im] (float4).
// qp = q * e^{+i l th};  kp = k * e^{-i l th};  lam = e^{-th0} e^{+i a th0}.
// ---------------------------------------------------------------------------
__global__ __launch_bounds__(256) void phase_kernel(
    float* __restrict__ qk, const float* __restrict__ a_ang,
    const float* __restrict__ p_angle, float* __restrict__ lam)
{
    const int idx = blockIdx.x * 256 + threadIdx.x;
    const int i = idx & 63;
    const int h = (idx >> 6) & 7;
    const int l = (idx >> 9) & (L_ - 1);
    const float th = p_angle[h * DQK_ + i];
    float s, c;
    __sincosf(th * (float)l, &s, &c);
    float4 qv = *(float4*)(qk + (size_t)idx * 4);
    float4 o;
    o.x = qv.x * c - qv.y * s;       // qp_re
    o.y = qv.x * s + qv.y * c;       // qp_im
    o.z = qv.z * c + qv.w * s;       // kp_re  (mult by conj)
    o.w = qv.w * c - qv.z * s;       // kp_im
    *(float4*)(qk + (size_t)idx * 4) = o;
    if (i == 0) {
        const int row = idx >> 6;                    // (b*L+l)*H + h
        const float a = a_ang[row];
        const float e = expf(-th);
        float ss, cs;
        __sincosf(a * th, &ss, &cs);
        lam[row * 2 + 0] = e * cs;
        lam[row * 2 + 1] = e * ss;
    }
}

// ---------------------------------------------------------------------------
// Recurrence: one block per (b,h). 512 threads: v = t&63, ig = t>>6.
//   Z_l = lam_l * Z_{l-1} + kp_l (x) v_l ;  h[l,v] = sum_i qp[l,i] Z_l[i,v]
//   init Z = hid * e^{i th};   hid_next = e^{i (L-1) th} * Z_final (pairs, ws)
// ---------------------------------------------------------------------------
__global__ __launch_bounds__(512) void recurrence_kernel(
    const float* __restrict__ qpkp, const float* __restrict__ vbuf,
    const float* __restrict__ lam,  const float* __restrict__ hidden,
    const float* __restrict__ p_angle, float* __restrict__ h_pre,
    float* __restrict__ hid_pairs)
{
    const int bh = blockIdx.x;
    const int b = bh >> 3, h = bh & 7;
    const int t = threadIdx.x;
    const int v = t & 63, ig = t >> 6;

    float Zr[8], Zi[8];
#pragma unroll
    for (int j = 0; j < 8; ++j) {
        const int i = ig * 8 + j;
        const float th = p_angle[h * DQK_ + i];
        float s, c;
        __sincosf(th, &s, &c);
        const float* hp = hidden + (((size_t)(b * H_ + h) * DQK_ + i) * DV_ + v) * 2;
        const float hr0 = hp[0], hi0 = hp[1];
        Zr[j] = hr0 * c - hi0 * s;
        Zi[j] = hr0 * s + hi0 * c;
    }

    __shared__ float red[8][DV_][2];

    for (int l = 0; l < L_; ++l) {
        const int row = (b * L_ + l) * H_ + h;
        const float lr = lam[row * 2 + 0];
        const float li = lam[row * 2 + 1];
        const float2 vv = *(const float2*)(vbuf + ((size_t)row * DV_ + v) * 2);
        const float4* qk = (const float4*)(qpkp + (size_t)row * DQK_ * 4);
        float pr = 0.f, pi = 0.f;
#pragma unroll
        for (int j = 0; j < 8; ++j) {
            const float4 q = qk[ig * 8 + j];   // qp_re, qp_im, kp_re, kp_im
            const float zr = Zr[j], zi = Zi[j];
            const float nr = lr * zr - li * zi + q.z * vv.x - q.w * vv.y;
            const float ni = lr * zi + li * zr + q.z * vv.y + q.w * vv.x;
            Zr[j] = nr; Zi[j] = ni;
            pr = fmaf(q.x, nr, pr); pr = fmaf(-q.y, ni, pr);
            pi = fmaf(q.x, ni, pi); pi = fmaf(q.y, nr, pi);
        }
        red[ig][v][0] = pr;
        red[ig][v][1] = pi;
        __syncthreads();
        if (ig == 0) {
            float sr = 0.f, si = 0.f;
#pragma unroll
            for (int g2 = 0; g2 < 8; ++g2) { sr += red[g2][v][0]; si += red[g2][v][1]; }
            *(float2*)(h_pre + ((size_t)row * DV_ + v) * 2) = make_float2(sr, si);
        }
        __syncthreads();
    }

    // hid_next = e^{i (L-1) th} * Z_final  (interleaved re/im into workspace)
#pragma unroll
    for (int j = 0; j < 8; ++j) {
        const int i = ig * 8 + j;
        const float th = p_angle[h * DQK_ + i] * (float)(L_ - 1);
        float s, c;
        __sincosf(th, &s, &c);
        float* op = hid_pairs + (((size_t)(b * H_ + h) * DQK_ + i) * DV_ + v) * 2;
        op[0] = Zr[j] * c - Zi[j] * s;
        op[1] = Zr[j] * s + Zi[j] * c;
    }
}

// ---------------------------------------------------------------------------
// Pack hid_next into d_out in whichever layout out_size dictates:
// real_only=1 -> dst[k] = src[2k]  (complex64 downcast to float32 real part)
// real_only=0 -> dst[k] = src[k]   (interleaved re/im pairs)
// ---------------------------------------------------------------------------
__global__ __launch_bounds__(256) void pack_hid(
    const float* __restrict__ src, float* __restrict__ dst,
    int n, int real_only)
{
    const int k = blockIdx.x * 256 + threadIdx.x;
    if (k < n) dst[k] = real_only ? src[2 * k] : src[k];
}

// ---------------------------------------------------------------------------
// GroupNorm over (V,2) per head + SiLU gating -> act[M_, H_*DV_*2]
// ---------------------------------------------------------------------------
__global__ __launch_bounds__(256) void gn_silu_kernel(
    const float* __restrict__ h_pre, const float* __restrict__ g,
    const float* __restrict__ gn_w, const float* __restrict__ gn_b,
    float* __restrict__ act)
{
    const int row = blockIdx.x;
    const int t = threadIdx.x;
    const int h = t >> 5, lane = t & 31;
    const float* hp = h_pre + ((size_t)row * H_ + h) * (DV_ * 2);
    float4 vals = *(const float4*)(hp + lane * 4);
    float sum = vals.x + vals.y + vals.z + vals.w;
    float ss  = vals.x * vals.x + vals.y * vals.y + vals.z * vals.z + vals.w * vals.w;
#pragma unroll
    for (int off = 16; off; off >>= 1) {
        sum += __shfl_xor(sum, off, 32);
        ss  += __shfl_xor(ss,  off, 32);
    }
    const float mean = sum * (1.f / 128.f);
    const float var  = ss * (1.f / 128.f) - mean * mean;
    const float scl  = rsqrtf(var + EPS_) * gn_w[h];
    const float sft  = gn_b[h];

    const float* gp = g + (size_t)row * (H_ * DV_ * 2) + h * (DV_ * 2) + lane * 4;
    float4 gv = *(const float4*)gp;
    float4 o;
    {
        float hn = (vals.x - mean) * scl + sft;
        o.x = hn * gv.x / (1.f + expf(-gv.x));
        hn = (vals.y - mean) * scl + sft;
        o.y = hn * gv.y / (1.f + expf(-gv.y));
        hn = (vals.z - mean) * scl + sft;
        o.z = hn * gv.z / (1.f + expf(-gv.z));
        hn = (vals.w - mean) * scl + sft;
        o.w = hn * gv.w / (1.f + expf(-gv.w));
    }
    *(float4*)(act + (size_t)row * (H_ * DV_ * 2) + h * (DV_ * 2) + lane * 4) = o;
}

// ---------------------------------------------------------------------------
// Launch
// ---------------------------------------------------------------------------
extern "C" void kernel_launch(void* const* d_in, const int* in_sizes, int n_in,
                              void* d_out, int out_size, void* d_ws, size_t ws_size,
                              hipStream_t stream)
{
    (void)in_sizes; (void)n_in; (void)ws_size;
    const float* x       = (const float*)d_in[0];
    const float* hidden  = (const float*)d_in[1];
    const float* w_qk    = (const float*)d_in[2];
    const float* b_qk    = (const float*)d_in[3];
    const float* w_v     = (const float*)d_in[4];
    const float* b_v     = (const float*)d_in[5];
    const float* w_g     = (const float*)d_in[6];
    const float* b_g     = (const float*)d_in[7];
    const float* w_a     = (const float*)d_in[8];
    const float* b_a     = (const float*)d_in[9];
    const float* w_y     = (const float*)d_in[10];
    const float* b_y     = (const float*)d_in[11];
    const float* gn_w    = (const float*)d_in[12];
    const float* gn_b    = (const float*)d_in[13];
    const float* p_angle = (const float*)d_in[14];

    float* y_out   = (float*)d_out;
    float* hid_out = (float*)d_out + (size_t)M_ * DIM_;
    const int hid_elems = out_size - M_ * DIM_;                 // 131072 or 262144
    const int real_only = (hid_elems == B_ * H_ * DQK_ * DV_) ? 1 : 0;

    float* ws = (float*)d_ws;
    float* buf_qk  = ws;                                   // 4,194,304 floats
    float* buf_v   = buf_qk  + (size_t)M_ * H_ * DQK_ * 4; // 2,097,152
    float* buf_g   = buf_v   + (size_t)M_ * H_ * DV_ * 2;  // 2,097,152
    float* buf_a   = buf_g   + (size_t)M_ * H_ * DV_ * 2;  // 16,384
    float* buf_lam = buf_a   + (size_t)M_ * H_;            // 32,768
    float* buf_h   = buf_lam + (size_t)M_ * H_ * 2;        // 2,097,152
    float* buf_hid = buf_h   + (size_t)M_ * H_ * DV_ * 2;  // 262,144
    float* buf_act = buf_qk;  // alias: qp/kp fully consumed before act written

    gemm_bias<<<dim3((H_*DQK_*4)/BN, M_/BM), 256, 0, stream>>>(
        x, w_qk, b_qk, buf_qk, M_, H_*DQK_*4, DIM_);
    gemm_bias<<<dim3((H_*DV_*2)/BN, M_/BM), 256, 0, stream>>>(
        x, w_v, b_v, buf_v, M_, H_*DV_*2, DIM_);
    gemm_bias<<<dim3((H_*DV_*2)/BN, M_/BM), 256, 0, stream>>>(
        x, w_g, b_g, buf_g, M_, H_*DV_*2, DIM_);
    gemm_a_kernel<<<(M_*H_)/4, 256, 0, stream>>>(x, w_a, b_a, buf_a);
    phase_kernel<<<(M_*H_*DQK_)/256, 256, 0, stream>>>(buf_qk, buf_a, p_angle, buf_lam);
    recurrence_kernel<<<B_*H_, 512, 0, stream>>>(
        buf_qk, buf_v, buf_lam, hidden, p_angle, buf_h, buf_hid);
    pack_hid<<<(hid_elems + 255) / 256, 256, 0, stream>>>(
        buf_hid, hid_out, hid_elems, real_only);
    gn_silu_kernel<<<M_, 256, 0, stream>>>(buf_h, buf_g, gn_w, gn_b, buf_act);
    gemm_bias<<<dim3(DIM_/BN, M_/BM), 256, 0, stream>>>(
        buf_act, w_y, b_y, y_out, M_, DIM_, DIM_);
}

// Round 3
// 461.851 us; speedup vs baseline: 1.9846x; 1.9846x over previous
//
#include <hip/hip_runtime.h>
#include <cstdint>
#include <cstddef>

// Problem constants
#define B_   4
#define L_   512
#define DIM_ 1024
#define H_   8
#define DQK_ 64
#define DV_  64
#define M_   (B_ * L_)          // 2048 rows
#define EPS_ 1e-5f

// ---------------------------------------------------------------------------
// Tiled fp32 GEMM: C[M,N] = A[M,K] @ W[N,K]^T + bias[N]
// ---------------------------------------------------------------------------
constexpr int BM = 64, BN = 64, BKk = 16;

__global__ __launch_bounds__(256) void gemm_bias(
    const float* __restrict__ A, const float* __restrict__ W,
    const float* __restrict__ bias, float* __restrict__ C,
    int M, int N, int K)
{
    __shared__ float As[BKk][BM + 4];
    __shared__ float Bs[BKk][BN + 4];

    const int t  = threadIdx.x;
    const int bm = blockIdx.y * BM;
    const int bn = blockIdx.x * BN;
    const int tm = (t >> 4) << 2;
    const int tn = (t & 15) << 2;
    const int lr = t >> 2;
    const int lk = (t & 3) << 2;

    float acc[4][4] = {};

    const float* Arow = A + (size_t)(bm + lr) * K + lk;
    const float* Wrow = W + (size_t)(bn + lr) * K + lk;

    for (int k0 = 0; k0 < K; k0 += BKk) {
        float4 av = *(const float4*)(Arow + k0);
        float4 wv = *(const float4*)(Wrow + k0);
        As[lk + 0][lr] = av.x; As[lk + 1][lr] = av.y;
        As[lk + 2][lr] = av.z; As[lk + 3][lr] = av.w;
        Bs[lk + 0][lr] = wv.x; Bs[lk + 1][lr] = wv.y;
        Bs[lk + 2][lr] = wv.z; Bs[lk + 3][lr] = wv.w;
        __syncthreads();
#pragma unroll
        for (int kk = 0; kk < BKk; ++kk) {
            float4 a = *(const float4*)&As[kk][tm];
            float4 b = *(const float4*)&Bs[kk][tn];
            float av4[4] = {a.x, a.y, a.z, a.w};
            float bv4[4] = {b.x, b.y, b.z, b.w};
#pragma unroll
            for (int i2 = 0; i2 < 4; ++i2)
#pragma unroll
                for (int j2 = 0; j2 < 4; ++j2)
                    acc[i2][j2] = fmaf(av4[i2], bv4[j2], acc[i2][j2]);
        }
        __syncthreads();
    }

    float4 bv;
    bv.x = bias[bn + tn + 0]; bv.y = bias[bn + tn + 1];
    bv.z = bias[bn + tn + 2]; bv.w = bias[bn + tn + 3];
#pragma unroll
    for (int i2 = 0; i2 < 4; ++i2) {
        float4 o;
        o.x = acc[i2][0] + bv.x; o.y = acc[i2][1] + bv.y;
        o.z = acc[i2][2] + bv.z; o.w = acc[i2][3] + bv.w;
        *(float4*)(C + (size_t)(bm + tm + i2) * N + bn + tn) = o;
    }
}

// ---------------------------------------------------------------------------
// Small GEMM for a_angle: out[M_,H_] = x @ w_a^T + b_a.
// ---------------------------------------------------------------------------
__global__ __launch_bounds__(256) void gemm_a_kernel(
    const float* __restrict__ x, const float* __restrict__ wa,
    const float* __restrict__ ba, float* __restrict__ out)
{
    const int w    = threadIdx.x >> 6;
    const int lane = threadIdx.x & 63;
    const int oidx = blockIdx.x * 4 + w;
    const int r = oidx >> 3, h = oidx & 7;
    const float* xr = x + (size_t)r * DIM_;
    const float* wr = wa + (size_t)h * DIM_;
    float p = 0.f;
    for (int k = lane; k < DIM_; k += 64)
        p = fmaf(xr[k], wr[k], p);
#pragma unroll
    for (int off = 32; off; off >>= 1)
        p += __shfl_down(p, off);
    if (lane == 0) out[oidx] = p + ba[h];
}

// ---------------------------------------------------------------------------
// Phase kernel: in-place transform qk proj -> (qp, kp).
// qk layout per (b,l,h,i): [q_re, q_im, k_re, k_im] (float4).
// qp = q * e^{+i l th};  kp = k * e^{-i l th}.
// ---------------------------------------------------------------------------
__global__ __launch_bounds__(256) void phase_kernel(
    float* __restrict__ qk, const float* __restrict__ p_angle)
{
    const int idx = blockIdx.x * 256 + threadIdx.x;
    const int i = idx & 63;
    const int h = (idx >> 6) & 7;
    const int l = (idx >> 9) & (L_ - 1);
    const float th = p_angle[h * DQK_ + i];
    float s, c;
    __sincosf(th * (float)l, &s, &c);
    float4 qv = *(float4*)(qk + (size_t)idx * 4);
    float4 o;
    o.x = qv.x * c - qv.y * s;
    o.y = qv.x * s + qv.y * c;
    o.z = qv.z * c + qv.w * s;
    o.w = qv.w * c - qv.z * s;
    *(float4*)(qk + (size_t)idx * 4) = o;
}

// ---------------------------------------------------------------------------
// chunkA: one block per (b,h,chunk).  C=64.
// Computes cumprods W/invW, scaled qp~/kp~, masked P = qp~ kp~^T,
// h_intra = P v  (written to h_pre), Zloc = G * (kp~^T v), G, W (stored).
// ---------------------------------------------------------------------------
__global__ __launch_bounds__(512) void chunkA(
    const float* __restrict__ qpkp, const float* __restrict__ vbuf,
    const float* __restrict__ a_ang, const float* __restrict__ p_angle,
    float* __restrict__ h_pre, float* __restrict__ Zloc,
    float* __restrict__ Gbuf, float* __restrict__ Wbuf)
{
    const int blk = blockIdx.x;
    const int c  = blk & 7;
    const int bh = blk >> 3;
    const int b = bh >> 3, h = bh & 7;
    const int t = threadIdx.x;
    const int l0 = c * 64;

    __shared__ float sQr[64][66], sQi[64][66];
    __shared__ float sKr[64][66], sKi[64][66];
    __shared__ float sVr[64][66], sVi[64][66];
    __shared__ float sW[64][4];     // Wr, Wi, invWr, invWi

    // wave 0: lambda cumprod scan (analytic lambda and 1/lambda)
    if (t < 64) {
        const float th0 = p_angle[h * DQK_];
        const float a = a_ang[((size_t)(b * L_) + l0 + t) * H_ + h];
        float sa, ca; __sincosf(a * th0, &sa, &ca);
        const float em = expf(-th0), ep = expf(th0);
        float lr = em * ca, li = em * sa;        // lambda
        float ir = ep * ca, ii = -ep * sa;       // 1/lambda
#pragma unroll
        for (int off = 1; off < 64; off <<= 1) {
            const float plr = __shfl_up(lr, off);
            const float pli = __shfl_up(li, off);
            const float pir = __shfl_up(ir, off);
            const float pii = __shfl_up(ii, off);
            if (t >= off) {
                float nr = lr * plr - li * pli;
                float ni = lr * pli + li * plr;
                lr = nr; li = ni;
                nr = ir * pir - ii * pii;
                ni = ir * pii + ii * pir;
                ir = nr; ii = ni;
            }
        }
        sW[t][0] = lr; sW[t][1] = li; sW[t][2] = ir; sW[t][3] = ii;
        Wbuf[((size_t)bh * L_ + l0 + t) * 2 + 0] = lr;
        Wbuf[((size_t)bh * L_ + l0 + t) * 2 + 1] = li;
        if (t == 63) {
            Gbuf[(bh * 8 + c) * 2 + 0] = lr;
            Gbuf[(bh * 8 + c) * 2 + 1] = li;
        }
    }
    __syncthreads();

    // load qp~, kp~, v into LDS
#pragma unroll
    for (int j = 0; j < 8; ++j) {
        const int idx = t * 8 + j;                 // 0..4095
        const int l = idx >> 6, i = idx & 63;
        const float4 q = *(const float4*)(qpkp + (((size_t)(b * L_ + l0 + l) * H_ + h) * 64 + i) * 4);
        const float wr = sW[l][0], wi = sW[l][1];
        const float xr = sW[l][2], xi = sW[l][3];
        sQr[l][i] = q.x * wr - q.y * wi;
        sQi[l][i] = q.x * wi + q.y * wr;
        sKr[l][i] = q.z * xr - q.w * xi;
        sKi[l][i] = q.z * xi + q.w * xr;
        const float2 vv = *(const float2*)(vbuf + (((size_t)(b * L_ + l0 + l) * H_ + h) * 64 + i) * 2);
        sVr[l][i] = vv.x; sVi[l][i] = vv.y;
    }
    __syncthreads();

    // P[l][m] = sum_i qp~[l][i] * kp~[m][i]   (thread: l = t>>3, 8 m's)
    const int pl = t >> 3;
    const int ps = t & 7;
    float Pr[8] = {}, Pi[8] = {};
    for (int i = 0; i < 64; ++i) {
        const float qr = sQr[pl][i], qi = sQi[pl][i];
#pragma unroll
        for (int mm = 0; mm < 8; ++mm) {
            const int m = ps * 8 + mm;
            const float kr = sKr[m][i], ki = sKi[m][i];
            Pr[mm] = fmaf(qr, kr, Pr[mm]); Pr[mm] = fmaf(-qi, ki, Pr[mm]);
            Pi[mm] = fmaf(qr, ki, Pi[mm]); Pi[mm] = fmaf(qi, kr, Pi[mm]);
        }
    }
    __syncthreads();
    // masked P -> sQ (reused as sP[l][m])
#pragma unroll
    for (int mm = 0; mm < 8; ++mm) {
        const int m = ps * 8 + mm;
        sQr[pl][m] = (m <= pl) ? Pr[mm] : 0.f;
        sQi[pl][m] = (m <= pl) ? Pi[mm] : 0.f;
    }
    __syncthreads();

    // h_intra[l][v] = sum_m sP[l][m] sV[m][v] ; Zloc[i][v] = sum_m kp~[m][i] sV[m][v]
    float Hr[8] = {}, Hi[8] = {};
    float Zr[8] = {}, Zi[8] = {};
    for (int m = 0; m < 64; ++m) {
        const float pr = sQr[pl][m], pi2 = sQi[pl][m];
        const float kr = sKr[m][pl], ki = sKi[m][pl];
#pragma unroll
        for (int vv = 0; vv < 8; ++vv) {
            const int v = ps * 8 + vv;
            const float vr = sVr[m][v], vi = sVi[m][v];
            Hr[vv] = fmaf(pr, vr, Hr[vv]); Hr[vv] = fmaf(-pi2, vi, Hr[vv]);
            Hi[vv] = fmaf(pr, vi, Hi[vv]); Hi[vv] = fmaf(pi2, vr, Hi[vv]);
            Zr[vv] = fmaf(kr, vr, Zr[vv]); Zr[vv] = fmaf(-ki, vi, Zr[vv]);
            Zi[vv] = fmaf(kr, vi, Zi[vv]); Zi[vv] = fmaf(ki, vr, Zi[vv]);
        }
    }

    const float Gr = sW[63][0], Gi = sW[63][1];
#pragma unroll
    for (int vv = 0; vv < 8; ++vv) {
        const int v = ps * 8 + vv;
        float* hp = h_pre + (((size_t)(b * L_ + l0 + pl) * H_ + h) * 64 + v) * 2;
        hp[0] = Hr[vv]; hp[1] = Hi[vv];
        float* zp = Zloc + (((size_t)(bh * 8 + c) * 4096) + pl * 64 + v) * 2;
        zp[0] = Gr * Zr[vv] - Gi * Zi[vv];
        zp[1] = Gr * Zi[vv] + Gi * Zr[vv];
    }
}

// ---------------------------------------------------------------------------
// scanB: sequential over 8 chunks, parallel over (b,h,i,v) entries.
// IN-PLACE: Zbuf holds Zloc on entry, Zin (incoming state per chunk) on exit.
// Also emits hid_next pairs = e^{i(L-1)th} * final state.
// ---------------------------------------------------------------------------
__global__ __launch_bounds__(512) void scanB(
    float* __restrict__ Zbuf, const float* __restrict__ Gbuf,
    const float* __restrict__ hidden, const float* __restrict__ p_angle,
    float* __restrict__ hid_pairs)
{
    const int bid = blockIdx.x;
    const int bh = bid >> 3, part = bid & 7;
    const int h = bh & 7;
    const int e = part * 512 + threadIdx.x;     // 0..4095 = i*64+v
    const int i = e >> 6;
    const float th = p_angle[h * 64 + i];
    float s, c; __sincosf(th, &s, &c);
    const float2 h0 = *(const float2*)(hidden + ((size_t)bh * 4096 + e) * 2);
    float zr = h0.x * c - h0.y * s;
    float zi = h0.x * s + h0.y * c;
#pragma unroll
    for (int ch = 0; ch < 8; ++ch) {
        float* zp = Zbuf + ((size_t)(bh * 8 + ch) * 4096 + e) * 2;
        const float zlr = zp[0], zli = zp[1];           // Zloc
        zp[0] = zr; zp[1] = zi;                          // overwrite with Zin
        const float gr = Gbuf[(bh * 8 + ch) * 2], gi = Gbuf[(bh * 8 + ch) * 2 + 1];
        const float nr = gr * zr - gi * zi + zlr;
        const float ni = gr * zi + gi * zr + zli;
        zr = nr; zi = ni;
    }
    float s2, c2; __sincosf(th * (float)(L_ - 1), &s2, &c2);
    float* op = hid_pairs + ((size_t)bh * 4096 + e) * 2;
    op[0] = zr * c2 - zi * s2;
    op[1] = zr * s2 + zi * c2;
}

// ---------------------------------------------------------------------------
// chunkC: h_pre += qp~ . Zin   (one block per (b,h,chunk))
// ---------------------------------------------------------------------------
__global__ __launch_bounds__(512) void chunkC(
    const float* __restrict__ qpkp, const float* __restrict__ Wbuf,
    const float* __restrict__ Zin, float* __restrict__ h_pre)
{
    const int blk = blockIdx.x;
    const int c = blk & 7, bh = blk >> 3;
    const int b = bh >> 3, h = bh & 7;
    const int t = threadIdx.x;
    const int l0 = c * 64;
    __shared__ float sQr[64][66], sQi[64][66];
    __shared__ float sZr[64][66], sZi[64][66];
    __shared__ float sWl[64][2];
    if (t < 64) {
        sWl[t][0] = Wbuf[((size_t)bh * L_ + l0 + t) * 2];
        sWl[t][1] = Wbuf[((size_t)bh * L_ + l0 + t) * 2 + 1];
    }
    __syncthreads();
#pragma unroll
    for (int j = 0; j < 8; ++j) {
        const int idx = t * 8 + j;
        const int l = idx >> 6, i = idx & 63;
        const float4 q = *(const float4*)(qpkp + (((size_t)(b * L_ + l0 + l) * H_ + h) * 64 + i) * 4);
        const float wr = sWl[l][0], wi = sWl[l][1];
        sQr[l][i] = q.x * wr - q.y * wi;
        sQi[l][i] = q.x * wi + q.y * wr;
        const float2 z = *(const float2*)(Zin + ((size_t)(bh * 8 + c) * 4096 + idx) * 2);
        sZr[l][i] = z.x; sZi[l][i] = z.y;   // [i_state][v]
    }
    __syncthreads();
    const int pl = t >> 3, ps = t & 7;
    float Hr[8] = {}, Hi[8] = {};
    for (int i = 0; i < 64; ++i) {
        const float qr = sQr[pl][i], qi = sQi[pl][i];
#pragma unroll
        for (int vv = 0; vv < 8; ++vv) {
            const int v = ps * 8 + vv;
            const float zr = sZr[i][v], zi = sZi[i][v];
            Hr[vv] = fmaf(qr, zr, Hr[vv]); Hr[vv] = fmaf(-qi, zi, Hr[vv]);
            Hi[vv] = fmaf(qr, zi, Hi[vv]); Hi[vv] = fmaf(qi, zr, Hi[vv]);
        }
    }
#pragma unroll
    for (int vv = 0; vv < 8; ++vv) {
        const int v = ps * 8 + vv;
        float* hp = h_pre + (((size_t)(b * L_ + l0 + pl) * H_ + h) * 64 + v) * 2;
        hp[0] += Hr[vv]; hp[1] += Hi[vv];
    }
}

// ---------------------------------------------------------------------------
// Pack hid_next into d_out per out_size layout.
// ---------------------------------------------------------------------------
__global__ __launch_bounds__(256) void pack_hid(
    const float* __restrict__ src, float* __restrict__ dst,
    int n, int real_only)
{
    const int k = blockIdx.x * 256 + threadIdx.x;
    if (k < n) dst[k] = real_only ? src[2 * k] : src[k];
}

// ---------------------------------------------------------------------------
// GroupNorm over (V,2) per head + SiLU gating -> act[M_, H_*DV_*2]
// ---------------------------------------------------------------------------
__global__ __launch_bounds__(256) void gn_silu_kernel(
    const float* __restrict__ h_pre, const float* __restrict__ g,
    const float* __restrict__ gn_w, const float* __restrict__ gn_b,
    float* __restrict__ act)
{
    const int row = blockIdx.x;
    const int t = threadIdx.x;
    const int h = t >> 5, lane = t & 31;
    const float* hp = h_pre + ((size_t)row * H_ + h) * (DV_ * 2);
    float4 vals = *(const float4*)(hp + lane * 4);
    float sum = vals.x + vals.y + vals.z + vals.w;
    float ss  = vals.x * vals.x + vals.y * vals.y + vals.z * vals.z + vals.w * vals.w;
#pragma unroll
    for (int off = 16; off; off >>= 1) {
        sum += __shfl_xor(sum, off, 32);
        ss  += __shfl_xor(ss,  off, 32);
    }
    const float mean = sum * (1.f / 128.f);
    const float var  = ss * (1.f / 128.f) - mean * mean;
    const float scl  = rsqrtf(var + EPS_) * gn_w[h];
    const float sft  = gn_b[h];

    const float* gp = g + (size_t)row * (H_ * DV_ * 2) + h * (DV_ * 2) + lane * 4;
    float4 gv = *(const float4*)gp;
    float4 o;
    {
        float hn = (vals.x - mean) * scl + sft;
        o.x = hn * gv.x / (1.f + expf(-gv.x));
        hn = (vals.y - mean) * scl + sft;
        o.y = hn * gv.y / (1.f + expf(-gv.y));
        hn = (vals.z - mean) * scl + sft;
        o.z = hn * gv.z / (1.f + expf(-gv.z));
        hn = (vals.w - mean) * scl + sft;
        o.w = hn * gv.w / (1.f + expf(-gv.w));
    }
    *(float4*)(act + (size_t)row * (H_ * DV_ * 2) + h * (DV_ * 2) + lane * 4) = o;
}

// ---------------------------------------------------------------------------
// Launch
// ---------------------------------------------------------------------------
extern "C" void kernel_launch(void* const* d_in, const int* in_sizes, int n_in,
                              void* d_out, int out_size, void* d_ws, size_t ws_size,
                              hipStream_t stream)
{
    (void)in_sizes; (void)n_in; (void)ws_size;
    const float* x       = (const float*)d_in[0];
    const float* hidden  = (const float*)d_in[1];
    const float* w_qk    = (const float*)d_in[2];
    const float* b_qk    = (const float*)d_in[3];
    const float* w_v     = (const float*)d_in[4];
    const float* b_v     = (const float*)d_in[5];
    const float* w_g     = (const float*)d_in[6];
    const float* b_g     = (const float*)d_in[7];
    const float* w_a     = (const float*)d_in[8];
    const float* b_a     = (const float*)d_in[9];
    const float* w_y     = (const float*)d_in[10];
    const float* b_y     = (const float*)d_in[11];
    const float* gn_w    = (const float*)d_in[12];
    const float* gn_b    = (const float*)d_in[13];
    const float* p_angle = (const float*)d_in[14];

    float* y_out   = (float*)d_out;
    float* hid_out = (float*)d_out + (size_t)M_ * DIM_;
    const int hid_elems = out_size - M_ * DIM_;
    const int real_only = (hid_elems == B_ * H_ * DQK_ * DV_) ? 1 : 0;

    float* ws = (float*)d_ws;
    float* buf_qk  = ws;                                   // 4,194,304 floats
    float* buf_v   = buf_qk  + (size_t)M_ * H_ * DQK_ * 4; // 2,097,152
    float* buf_g   = buf_v   + (size_t)M_ * H_ * DV_ * 2;  // 2,097,152
    float* buf_a   = buf_g   + (size_t)M_ * H_ * DV_ * 2;  // 16,384
    float* buf_W   = buf_a   + (size_t)M_ * H_;            // 32,768
    float* buf_G   = buf_W   + 32 * L_ * 2;                // 512
    float* buf_Z   = buf_G   + 512;                        // 2,097,152 (Zloc->Zin)
    float* buf_h   = buf_Z   + (size_t)32 * 8 * 4096 * 2;  // 2,097,152
    float* buf_hid = buf_h   + (size_t)M_ * H_ * DV_ * 2;  // 262,144
    float* buf_act = buf_qk;  // alias: qp/kp fully consumed before act written

    gemm_bias<<<dim3((H_*DQK_*4)/BN, M_/BM), 256, 0, stream>>>(
        x, w_qk, b_qk, buf_qk, M_, H_*DQK_*4, DIM_);
    gemm_bias<<<dim3((H_*DV_*2)/BN, M_/BM), 256, 0, stream>>>(
        x, w_v, b_v, buf_v, M_, H_*DV_*2, DIM_);
    gemm_bias<<<dim3((H_*DV_*2)/BN, M_/BM), 256, 0, stream>>>(
        x, w_g, b_g, buf_g, M_, H_*DV_*2, DIM_);
    gemm_a_kernel<<<(M_*H_)/4, 256, 0, stream>>>(x, w_a, b_a, buf_a);
    phase_kernel<<<(M_*H_*DQK_)/256, 256, 0, stream>>>(buf_qk, p_angle);

    chunkA<<<B_*H_*8, 512, 0, stream>>>(
        buf_qk, buf_v, buf_a, p_angle, buf_h, buf_Z, buf_G, buf_W);
    scanB<<<B_*H_*8, 512, 0, stream>>>(
        buf_Z, buf_G, hidden, p_angle, buf_hid);
    chunkC<<<B_*H_*8, 512, 0, stream>>>(
        buf_qk, buf_W, buf_Z, buf_h);

    pack_hid<<<(hid_elems + 255) / 256, 256, 0, stream>>>(
        buf_hid, hid_out, hid_elems, real_only);
    gn_silu_kernel<<<M_, 256, 0, stream>>>(buf_h, buf_g, gn_w, gn_b, buf_act);
    gemm_bias<<<dim3(DIM_/BN, M_/BM), 256, 0, stream>>>(
        buf_act, w_y, b_y, y_out, M_, DIM_, DIM_);
}

// Round 4
// 207.049 us; speedup vs baseline: 4.4270x; 2.2306x over previous
//
#include <hip/hip_runtime.h>
#include <cstdint>
#include <cstddef>

// Problem constants
#define B_   4
#define L_   512
#define DIM_ 1024
#define H_   8
#define DQK_ 64
#define DV_  64
#define M_   (B_ * L_)          // 2048 rows
#define EPS_ 1e-5f

typedef __attribute__((ext_vector_type(8))) short short8;
typedef __attribute__((ext_vector_type(4))) float f32x4;

// ---------------------------------------------------------------------------
// fp32 -> bf16 (RTNE) helpers
// ---------------------------------------------------------------------------
__device__ __forceinline__ unsigned short f2bf(float f) {
    uint32_t u = __float_as_uint(f);
    u += 0x7FFFu + ((u >> 16) & 1u);
    return (unsigned short)(u >> 16);
}

__global__ __launch_bounds__(256) void cast4_kernel(
    const float* __restrict__ src, unsigned short* __restrict__ dst, int n4)
{
    const int i = blockIdx.x * 256 + threadIdx.x;
    if (i < n4) {
        const float4 v = ((const float4*)src)[i];
        ushort4 o;
        o.x = f2bf(v.x); o.y = f2bf(v.y); o.z = f2bf(v.z); o.w = f2bf(v.w);
        ((ushort4*)dst)[i] = o;
    }
}

// ---------------------------------------------------------------------------
// bf16 MFMA GEMM (m97 structure): C = A[M,K](bf16) @ W[N,K]^T(bf16) + bias.
// 128x128 tile, BK=32, 256 threads (4 waves, 2x2 quadrants of 64x64),
// global_load_lds width-16 staging, fp32 output.
// Output may be split at column Nsplit into (C0,ld0,bias0) / (C1,ld1,bias1).
// ---------------------------------------------------------------------------
__device__ __forceinline__ void gload16(const void* g, void* l) {
    __builtin_amdgcn_global_load_lds(
        (const __attribute__((address_space(1))) unsigned int*)g,
        (__attribute__((address_space(3))) unsigned int*)l, 16, 0, 0);
}

__global__ __launch_bounds__(256) void gemm_mfma(
    const unsigned short* __restrict__ A, const unsigned short* __restrict__ W,
    const float* __restrict__ bias0, const float* __restrict__ bias1,
    float* __restrict__ C0, float* __restrict__ C1,
    int Nsplit, int ld0, int ld1, int M, int N, int K)
{
    __shared__ unsigned short sA[128 * 32];
    __shared__ unsigned short sB[128 * 32];

    const int t    = threadIdx.x;
    const int lane = t & 63;
    const int wv   = t >> 6;
    const int bm   = blockIdx.y * 128;
    const int bn   = blockIdx.x * 128;
    const int wr   = wv >> 1, wc = wv & 1;
    const int fr   = lane & 15;      // fragment outer index
    const int fq   = lane >> 4;      // k-group

    // staging coordinates (per wave chunk c2 = wv*2+q covers 16 rows)
    const int srow = lane >> 2;          // 0..15
    const int ske  = (lane & 3) * 8;     // k element offset 0,8,16,24

    f32x4 acc[4][4] = {};

    for (int k0 = 0; k0 < K; k0 += 32) {
#pragma unroll
        for (int q = 0; q < 2; ++q) {
            const int c2 = wv * 2 + q;
            gload16(A + (size_t)(bm + c2 * 16 + srow) * K + k0 + ske,
                    (char*)sA + c2 * 1024);
            gload16(W + (size_t)(bn + c2 * 16 + srow) * K + k0 + ske,
                    (char*)sB + c2 * 1024);
        }
        __syncthreads();

        short8 af[4], bf[4];
#pragma unroll
        for (int mi = 0; mi < 4; ++mi)
            af[mi] = *(const short8*)&sA[(wr * 64 + mi * 16 + fr) * 32 + fq * 8];
#pragma unroll
        for (int ni = 0; ni < 4; ++ni)
            bf[ni] = *(const short8*)&sB[(wc * 64 + ni * 16 + fr) * 32 + fq * 8];
#pragma unroll
        for (int mi = 0; mi < 4; ++mi)
#pragma unroll
            for (int ni = 0; ni < 4; ++ni)
                acc[mi][ni] = __builtin_amdgcn_mfma_f32_16x16x32_bf16(
                    af[mi], bf[ni], acc[mi][ni], 0, 0, 0);
        __syncthreads();
    }

    // epilogue: column-uniform split per block
    float* Cb; const float* bb; int coff, ldc;
    if (bn < Nsplit) { Cb = C0; bb = bias0; coff = 0;      ldc = ld0; }
    else             { Cb = C1; bb = bias1; coff = Nsplit; ldc = ld1; }

#pragma unroll
    for (int mi = 0; mi < 4; ++mi)
#pragma unroll
        for (int ni = 0; ni < 4; ++ni) {
            const int col = bn + wc * 64 + ni * 16 + fr - coff;
            const float bv = bb[col];
#pragma unroll
            for (int r = 0; r < 4; ++r) {
                const int row = bm + wr * 64 + mi * 16 + fq * 4 + r;
                Cb[(size_t)row * ldc + col] = acc[mi][ni][r] + bv;
            }
        }
}

// ---------------------------------------------------------------------------
// Small GEMM for a_angle: out[M_,H_] = x @ w_a^T + b_a.
// ---------------------------------------------------------------------------
__global__ __launch_bounds__(256) void gemm_a_kernel(
    const float* __restrict__ x, const float* __restrict__ wa,
    const float* __restrict__ ba, float* __restrict__ out)
{
    const int w    = threadIdx.x >> 6;
    const int lane = threadIdx.x & 63;
    const int oidx = blockIdx.x * 4 + w;
    const int r = oidx >> 3, h = oidx & 7;
    const float* xr = x + (size_t)r * DIM_;
    const float* wr = wa + (size_t)h * DIM_;
    float p = 0.f;
    for (int k = lane; k < DIM_; k += 64)
        p = fmaf(xr[k], wr[k], p);
#pragma unroll
    for (int off = 32; off; off >>= 1)
        p += __shfl_down(p, off);
    if (lane == 0) out[oidx] = p + ba[h];
}

// ---------------------------------------------------------------------------
// Phase kernel: in-place transform qk proj -> (qp, kp).
// ---------------------------------------------------------------------------
__global__ __launch_bounds__(256) void phase_kernel(
    float* __restrict__ qk, const float* __restrict__ p_angle)
{
    const int idx = blockIdx.x * 256 + threadIdx.x;
    const int i = idx & 63;
    const int h = (idx >> 6) & 7;
    const int l = (idx >> 9) & (L_ - 1);
    const float th = p_angle[h * DQK_ + i];
    float s, c;
    __sincosf(th * (float)l, &s, &c);
    float4 qv = *(float4*)(qk + (size_t)idx * 4);
    float4 o;
    o.x = qv.x * c - qv.y * s;
    o.y = qv.x * s + qv.y * c;
    o.z = qv.z * c + qv.w * s;
    o.w = qv.w * c - qv.z * s;
    *(float4*)(qk + (size_t)idx * 4) = o;
}

// ---------------------------------------------------------------------------
// chunkA: one block per (b,h,chunk).  C=64.
// ---------------------------------------------------------------------------
__global__ __launch_bounds__(512) void chunkA(
    const float* __restrict__ qpkp, const float* __restrict__ vbuf,
    const float* __restrict__ a_ang, const float* __restrict__ p_angle,
    float* __restrict__ h_pre, float* __restrict__ Zloc,
    float* __restrict__ Gbuf, float* __restrict__ Wbuf)
{
    const int blk = blockIdx.x;
    const int c  = blk & 7;
    const int bh = blk >> 3;
    const int b = bh >> 3, h = bh & 7;
    const int t = threadIdx.x;
    const int l0 = c * 64;

    __shared__ float sQr[64][66], sQi[64][66];
    __shared__ float sKr[64][66], sKi[64][66];
    __shared__ float sVr[64][66], sVi[64][66];
    __shared__ float sW[64][4];

    if (t < 64) {
        const float th0 = p_angle[h * DQK_];
        const float a = a_ang[((size_t)(b * L_) + l0 + t) * H_ + h];
        float sa, ca; __sincosf(a * th0, &sa, &ca);
        const float em = expf(-th0), ep = expf(th0);
        float lr = em * ca, li = em * sa;
        float ir = ep * ca, ii = -ep * sa;
#pragma unroll
        for (int off = 1; off < 64; off <<= 1) {
            const float plr = __shfl_up(lr, off);
            const float pli = __shfl_up(li, off);
            const float pir = __shfl_up(ir, off);
            const float pii = __shfl_up(ii, off);
            if (t >= off) {
                float nr = lr * plr - li * pli;
                float ni = lr * pli + li * plr;
                lr = nr; li = ni;
                nr = ir * pir - ii * pii;
                ni = ir * pii + ii * pir;
                ir = nr; ii = ni;
            }
        }
        sW[t][0] = lr; sW[t][1] = li; sW[t][2] = ir; sW[t][3] = ii;
        Wbuf[((size_t)bh * L_ + l0 + t) * 2 + 0] = lr;
        Wbuf[((size_t)bh * L_ + l0 + t) * 2 + 1] = li;
        if (t == 63) {
            Gbuf[(bh * 8 + c) * 2 + 0] = lr;
            Gbuf[(bh * 8 + c) * 2 + 1] = li;
        }
    }
    __syncthreads();

#pragma unroll
    for (int j = 0; j < 8; ++j) {
        const int idx = t * 8 + j;
        const int l = idx >> 6, i = idx & 63;
        const float4 q = *(const float4*)(qpkp + (((size_t)(b * L_ + l0 + l) * H_ + h) * 64 + i) * 4);
        const float wr = sW[l][0], wi = sW[l][1];
        const float xr = sW[l][2], xi = sW[l][3];
        sQr[l][i] = q.x * wr - q.y * wi;
        sQi[l][i] = q.x * wi + q.y * wr;
        sKr[l][i] = q.z * xr - q.w * xi;
        sKi[l][i] = q.z * xi + q.w * xr;
        const float2 vv = *(const float2*)(vbuf + (((size_t)(b * L_ + l0 + l) * H_ + h) * 64 + i) * 2);
        sVr[l][i] = vv.x; sVi[l][i] = vv.y;
    }
    __syncthreads();

    const int pl = t >> 3;
    const int ps = t & 7;
    float Pr[8] = {}, Pi[8] = {};
    for (int i = 0; i < 64; ++i) {
        const float qr = sQr[pl][i], qi = sQi[pl][i];
#pragma unroll
        for (int mm = 0; mm < 8; ++mm) {
            const int m = ps * 8 + mm;
            const float kr = sKr[m][i], ki = sKi[m][i];
            Pr[mm] = fmaf(qr, kr, Pr[mm]); Pr[mm] = fmaf(-qi, ki, Pr[mm]);
            Pi[mm] = fmaf(qr, ki, Pi[mm]); Pi[mm] = fmaf(qi, kr, Pi[mm]);
        }
    }
    __syncthreads();
#pragma unroll
    for (int mm = 0; mm < 8; ++mm) {
        const int m = ps * 8 + mm;
        sQr[pl][m] = (m <= pl) ? Pr[mm] : 0.f;
        sQi[pl][m] = (m <= pl) ? Pi[mm] : 0.f;
    }
    __syncthreads();

    float Hr[8] = {}, Hi[8] = {};
    float Zr[8] = {}, Zi[8] = {};
    for (int m = 0; m < 64; ++m) {
        const float pr = sQr[pl][m], pi2 = sQi[pl][m];
        const float kr = sKr[m][pl], ki = sKi[m][pl];
#pragma unroll
        for (int vv = 0; vv < 8; ++vv) {
            const int v = ps * 8 + vv;
            const float vr = sVr[m][v], vi = sVi[m][v];
            Hr[vv] = fmaf(pr, vr, Hr[vv]); Hr[vv] = fmaf(-pi2, vi, Hr[vv]);
            Hi[vv] = fmaf(pr, vi, Hi[vv]); Hi[vv] = fmaf(pi2, vr, Hi[vv]);
            Zr[vv] = fmaf(kr, vr, Zr[vv]); Zr[vv] = fmaf(-ki, vi, Zr[vv]);
            Zi[vv] = fmaf(kr, vi, Zi[vv]); Zi[vv] = fmaf(ki, vr, Zi[vv]);
        }
    }

    const float Gr = sW[63][0], Gi = sW[63][1];
#pragma unroll
    for (int vv = 0; vv < 8; ++vv) {
        const int v = ps * 8 + vv;
        float* hp = h_pre + (((size_t)(b * L_ + l0 + pl) * H_ + h) * 64 + v) * 2;
        hp[0] = Hr[vv]; hp[1] = Hi[vv];
        float* zp = Zloc + (((size_t)(bh * 8 + c) * 4096) + pl * 64 + v) * 2;
        zp[0] = Gr * Zr[vv] - Gi * Zi[vv];
        zp[1] = Gr * Zi[vv] + Gi * Zr[vv];
    }
}

// ---------------------------------------------------------------------------
// scanB: sequential over 8 chunks, parallel over entries. In-place Zloc->Zin.
// ---------------------------------------------------------------------------
__global__ __launch_bounds__(512) void scanB(
    float* __restrict__ Zbuf, const float* __restrict__ Gbuf,
    const float* __restrict__ hidden, const float* __restrict__ p_angle,
    float* __restrict__ hid_pairs)
{
    const int bid = blockIdx.x;
    const int bh = bid >> 3, part = bid & 7;
    const int h = bh & 7;
    const int e = part * 512 + threadIdx.x;
    const int i = e >> 6;
    const float th = p_angle[h * 64 + i];
    float s, c; __sincosf(th, &s, &c);
    const float2 h0 = *(const float2*)(hidden + ((size_t)bh * 4096 + e) * 2);
    float zr = h0.x * c - h0.y * s;
    float zi = h0.x * s + h0.y * c;
#pragma unroll
    for (int ch = 0; ch < 8; ++ch) {
        float* zp = Zbuf + ((size_t)(bh * 8 + ch) * 4096 + e) * 2;
        const float zlr = zp[0], zli = zp[1];
        zp[0] = zr; zp[1] = zi;
        const float gr = Gbuf[(bh * 8 + ch) * 2], gi = Gbuf[(bh * 8 + ch) * 2 + 1];
        const float nr = gr * zr - gi * zi + zlr;
        const float ni = gr * zi + gi * zr + zli;
        zr = nr; zi = ni;
    }
    float s2, c2; __sincosf(th * (float)(L_ - 1), &s2, &c2);
    float* op = hid_pairs + ((size_t)bh * 4096 + e) * 2;
    op[0] = zr * c2 - zi * s2;
    op[1] = zr * s2 + zi * c2;
}

// ---------------------------------------------------------------------------
// chunkC: h_pre += qp~ . Zin
// ---------------------------------------------------------------------------
__global__ __launch_bounds__(512) void chunkC(
    const float* __restrict__ qpkp, const float* __restrict__ Wbuf,
    const float* __restrict__ Zin, float* __restrict__ h_pre)
{
    const int blk = blockIdx.x;
    const int c = blk & 7, bh = blk >> 3;
    const int b = bh >> 3, h = bh & 7;
    const int t = threadIdx.x;
    const int l0 = c * 64;
    __shared__ float sQr[64][66], sQi[64][66];
    __shared__ float sZr[64][66], sZi[64][66];
    __shared__ float sWl[64][2];
    if (t < 64) {
        sWl[t][0] = Wbuf[((size_t)bh * L_ + l0 + t) * 2];
        sWl[t][1] = Wbuf[((size_t)bh * L_ + l0 + t) * 2 + 1];
    }
    __syncthreads();
#pragma unroll
    for (int j = 0; j < 8; ++j) {
        const int idx = t * 8 + j;
        const int l = idx >> 6, i = idx & 63;
        const float4 q = *(const float4*)(qpkp + (((size_t)(b * L_ + l0 + l) * H_ + h) * 64 + i) * 4);
        const float wr = sWl[l][0], wi = sWl[l][1];
        sQr[l][i] = q.x * wr - q.y * wi;
        sQi[l][i] = q.x * wi + q.y * wr;
        const float2 z = *(const float2*)(Zin + ((size_t)(bh * 8 + c) * 4096 + idx) * 2);
        sZr[l][i] = z.x; sZi[l][i] = z.y;
    }
    __syncthreads();
    const int pl = t >> 3, ps = t & 7;
    float Hr[8] = {}, Hi[8] = {};
    for (int i = 0; i < 64; ++i) {
        const float qr = sQr[pl][i], qi = sQi[pl][i];
#pragma unroll
        for (int vv = 0; vv < 8; ++vv) {
            const int v = ps * 8 + vv;
            const float zr = sZr[i][v], zi = sZi[i][v];
            Hr[vv] = fmaf(qr, zr, Hr[vv]); Hr[vv] = fmaf(-qi, zi, Hr[vv]);
            Hi[vv] = fmaf(qr, zi, Hi[vv]); Hi[vv] = fmaf(qi, zr, Hi[vv]);
        }
    }
#pragma unroll
    for (int vv = 0; vv < 8; ++vv) {
        const int v = ps * 8 + vv;
        float* hp = h_pre + (((size_t)(b * L_ + l0 + pl) * H_ + h) * 64 + v) * 2;
        hp[0] += Hr[vv]; hp[1] += Hi[vv];
    }
}

// ---------------------------------------------------------------------------
// Pack hid_next into d_out per out_size layout.
// ---------------------------------------------------------------------------
__global__ __launch_bounds__(256) void pack_hid(
    const float* __restrict__ src, float* __restrict__ dst,
    int n, int real_only)
{
    const int k = blockIdx.x * 256 + threadIdx.x;
    if (k < n) dst[k] = real_only ? src[2 * k] : src[k];
}

// ---------------------------------------------------------------------------
// GroupNorm + SiLU gate -> act (bf16) [M_, 1024]
// ---------------------------------------------------------------------------
__global__ __launch_bounds__(256) void gn_silu_kernel(
    const float* __restrict__ h_pre, const float* __restrict__ g,
    const float* __restrict__ gn_w, const float* __restrict__ gn_b,
    unsigned short* __restrict__ act)
{
    const int row = blockIdx.x;
    const int t = threadIdx.x;
    const int h = t >> 5, lane = t & 31;
    const float* hp = h_pre + ((size_t)row * H_ + h) * (DV_ * 2);
    float4 vals = *(const float4*)(hp + lane * 4);
    float sum = vals.x + vals.y + vals.z + vals.w;
    float ss  = vals.x * vals.x + vals.y * vals.y + vals.z * vals.z + vals.w * vals.w;
#pragma unroll
    for (int off = 16; off; off >>= 1) {
        sum += __shfl_xor(sum, off, 32);
        ss  += __shfl_xor(ss,  off, 32);
    }
    const float mean = sum * (1.f / 128.f);
    const float var  = ss * (1.f / 128.f) - mean * mean;
    const float scl  = rsqrtf(var + EPS_) * gn_w[h];
    const float sft  = gn_b[h];

    const float* gp = g + (size_t)row * (H_ * DV_ * 2) + h * (DV_ * 2) + lane * 4;
    float4 gv = *(const float4*)gp;
    float o0, o1, o2, o3;
    {
        float hn = (vals.x - mean) * scl + sft;
        o0 = hn * gv.x / (1.f + expf(-gv.x));
        hn = (vals.y - mean) * scl + sft;
        o1 = hn * gv.y / (1.f + expf(-gv.y));
        hn = (vals.z - mean) * scl + sft;
        o2 = hn * gv.z / (1.f + expf(-gv.z));
        hn = (vals.w - mean) * scl + sft;
        o3 = hn * gv.w / (1.f + expf(-gv.w));
    }
    ushort4 ov;
    ov.x = f2bf(o0); ov.y = f2bf(o1); ov.z = f2bf(o2); ov.w = f2bf(o3);
    *(ushort4*)(act + (size_t)row * (H_ * DV_ * 2) + h * (DV_ * 2) + lane * 4) = ov;
}

// ---------------------------------------------------------------------------
// Launch
// ---------------------------------------------------------------------------
extern "C" void kernel_launch(void* const* d_in, const int* in_sizes, int n_in,
                              void* d_out, int out_size, void* d_ws, size_t ws_size,
                              hipStream_t stream)
{
    (void)in_sizes; (void)n_in; (void)ws_size;
    const float* x       = (const float*)d_in[0];
    const float* hidden  = (const float*)d_in[1];
    const float* w_qk    = (const float*)d_in[2];
    const float* b_qk    = (const float*)d_in[3];
    const float* w_v     = (const float*)d_in[4];
    const float* b_v     = (const float*)d_in[5];
    const float* w_g     = (const float*)d_in[6];
    const float* b_g     = (const float*)d_in[7];
    const float* w_a     = (const float*)d_in[8];
    const float* b_a     = (const float*)d_in[9];
    const float* w_y     = (const float*)d_in[10];
    const float* b_y     = (const float*)d_in[11];
    const float* gn_w    = (const float*)d_in[12];
    const float* gn_b    = (const float*)d_in[13];
    const float* p_angle = (const float*)d_in[14];

    float* y_out   = (float*)d_out;
    float* hid_out = (float*)d_out + (size_t)M_ * DIM_;
    const int hid_elems = out_size - M_ * DIM_;
    const int real_only = (hid_elems == B_ * H_ * DQK_ * DV_) ? 1 : 0;

    float* ws = (float*)d_ws;
    float* buf_qk  = ws;                                   // 4,194,304 floats
    float* buf_v   = buf_qk  + (size_t)M_ * H_ * DQK_ * 4; // 2,097,152
    float* buf_g   = buf_v   + (size_t)M_ * H_ * DV_ * 2;  // 2,097,152
    float* buf_a   = buf_g   + (size_t)M_ * H_ * DV_ * 2;  // 16,384
    float* buf_W   = buf_a   + (size_t)M_ * H_;            // 32,768
    float* buf_G   = buf_W   + 32 * L_ * 2;                // 512
    float* buf_Z   = buf_G   + 512;                        // 2,097,152
    float* buf_h   = buf_Z   + (size_t)32 * 8 * 4096 * 2;  // 2,097,152
    float* buf_hid = buf_h   + (size_t)M_ * H_ * DV_ * 2;  // 262,144
    float* buf_wyb = buf_hid + 262144;                     // 524,288 (bf16 w_y)

    // bf16 aliases (lifetimes disjoint from the aliased fp32 buffers)
    unsigned short* wqkb = (unsigned short*)buf_Z;                    // 2M bf16
    unsigned short* wvb  = (unsigned short*)(buf_Z + 1048576);        // 1M bf16
    unsigned short* wgb  = (unsigned short*)(buf_Z + 1572864);        // 1M bf16
    unsigned short* xb   = (unsigned short*)buf_h;                    // 2M bf16
    unsigned short* wyb  = (unsigned short*)buf_wyb;                  // 1M bf16
    unsigned short* actb = (unsigned short*)buf_qk;                   // 2M bf16

    // casts
    cast4_kernel<<<2048, 256, 0, stream>>>(x,    xb,   524288);
    cast4_kernel<<<2048, 256, 0, stream>>>(w_qk, wqkb, 524288);
    cast4_kernel<<<1024, 256, 0, stream>>>(w_v,  wvb,  262144);
    cast4_kernel<<<1024, 256, 0, stream>>>(w_g,  wgb,  262144);
    cast4_kernel<<<1024, 256, 0, stream>>>(w_y,  wyb,  262144);

    // qk projection: M=2048, N=2048, K=1024
    gemm_mfma<<<dim3(16, 16), 256, 0, stream>>>(
        xb, wqkb, b_qk, b_qk, buf_qk, buf_qk, 2048, 2048, 2048, M_, 2048, DIM_);
    // v+g fused: W = [wvb; wgb] contiguous, N=2048, split at 1024
    gemm_mfma<<<dim3(16, 16), 256, 0, stream>>>(
        xb, wvb, b_v, b_g, buf_v, buf_g, 1024, 1024, 1024, M_, 2048, DIM_);

    gemm_a_kernel<<<(M_*H_)/4, 256, 0, stream>>>(x, w_a, b_a, buf_a);
    phase_kernel<<<(M_*H_*DQK_)/256, 256, 0, stream>>>(buf_qk, p_angle);

    chunkA<<<B_*H_*8, 512, 0, stream>>>(
        buf_qk, buf_v, buf_a, p_angle, buf_h, buf_Z, buf_G, buf_W);
    scanB<<<B_*H_*8, 512, 0, stream>>>(
        buf_Z, buf_G, hidden, p_angle, buf_hid);
    chunkC<<<B_*H_*8, 512, 0, stream>>>(
        buf_qk, buf_W, buf_Z, buf_h);

    pack_hid<<<(hid_elems + 255) / 256, 256, 0, stream>>>(
        buf_hid, hid_out, hid_elems, real_only);
    gn_silu_kernel<<<M_, 256, 0, stream>>>(buf_h, buf_g, gn_w, gn_b, actb);

    // y projection: M=2048, N=1024, K=1024
    gemm_mfma<<<dim3(8, 16), 256, 0, stream>>>(
        actb, wyb, b_y, b_y, y_out, y_out, 1024, 1024, 1024, M_, 1024, DIM_);
}

// Round 5
// 141.594 us; speedup vs baseline: 6.4734x; 1.4623x over previous
//
#include <hip/hip_runtime.h>
#include <cstdint>
#include <cstddef>

// Problem constants
#define B_   4
#define L_   512
#define DIM_ 1024
#define H_   8
#define DQK_ 64
#define DV_  64
#define M_   (B_ * L_)          // 2048 rows
#define EPS_ 1e-5f

typedef __attribute__((ext_vector_type(8))) short short8;
typedef __attribute__((ext_vector_type(4))) float f32x4;

// ---------------------------------------------------------------------------
// fp32 -> bf16 (RTNE)
// ---------------------------------------------------------------------------
__device__ __forceinline__ unsigned short f2bf(float f) {
    uint32_t u = __float_as_uint(f);
    u += 0x7FFFu + ((u >> 16) & 1u);
    return (unsigned short)(u >> 16);
}

__device__ __forceinline__ f32x4 mm16(short8 a, short8 b, f32x4 c) {
    return __builtin_amdgcn_mfma_f32_16x16x32_bf16(a, b, c, 0, 0, 0);
}

// 64x64 bf16 plane with XOR swizzle: element (r,c) at byte r*128 + ((2c)^((r&7)<<4))
__device__ __forceinline__ int swoff(int r, int kb) {
    return r * 128 + (kb ^ ((r & 7) << 4));
}
__device__ __forceinline__ short8 frag(const unsigned short* p, int strip, int ks, int lane) {
    const int fr = lane & 15, fq = lane >> 4;
    const int r = strip * 16 + fr;
    return *(const short8*)((const char*)p + swoff(r, ks * 64 + fq * 16));
}

// ---------------------------------------------------------------------------
// Fused cast: x, w_qk, w_v, w_g, w_y -> bf16
// ---------------------------------------------------------------------------
__global__ __launch_bounds__(256) void cast_all(
    const float* __restrict__ x, const float* __restrict__ wqk,
    const float* __restrict__ wv, const float* __restrict__ wg,
    const float* __restrict__ wy,
    unsigned short* __restrict__ xb, unsigned short* __restrict__ wqkb,
    unsigned short* __restrict__ wvb, unsigned short* __restrict__ wgb,
    unsigned short* __restrict__ wyb)
{
    const int blk = blockIdx.x;
    const float* src; unsigned short* dst; int base;
    if      (blk < 2048) { src = x;   dst = xb;   base = blk; }
    else if (blk < 4096) { src = wqk; dst = wqkb; base = blk - 2048; }
    else if (blk < 5120) { src = wv;  dst = wvb;  base = blk - 4096; }
    else if (blk < 6144) { src = wg;  dst = wgb;  base = blk - 5120; }
    else                 { src = wy;  dst = wyb;  base = blk - 6144; }
    const int i = base * 256 + threadIdx.x;
    const float4 v = ((const float4*)src)[i];
    ushort4 o;
    o.x = f2bf(v.x); o.y = f2bf(v.y); o.z = f2bf(v.z); o.w = f2bf(v.w);
    ((ushort4*)dst)[i] = o;
}

// ---------------------------------------------------------------------------
// bf16 MFMA GEMM (m97 structure), split-output variant. (unchanged, passing)
// ---------------------------------------------------------------------------
__device__ __forceinline__ void gload16(const void* g, void* l) {
    __builtin_amdgcn_global_load_lds(
        (const __attribute__((address_space(1))) unsigned int*)g,
        (__attribute__((address_space(3))) unsigned int*)l, 16, 0, 0);
}

__global__ __launch_bounds__(256) void gemm_mfma(
    const unsigned short* __restrict__ A, const unsigned short* __restrict__ W,
    const float* __restrict__ bias0, const float* __restrict__ bias1,
    float* __restrict__ C0, float* __restrict__ C1,
    int Nsplit, int ld0, int ld1, int M, int N, int K)
{
    __shared__ unsigned short sA[128 * 32];
    __shared__ unsigned short sB[128 * 32];

    const int t    = threadIdx.x;
    const int lane = t & 63;
    const int wv   = t >> 6;
    const int bm   = blockIdx.y * 128;
    const int bn   = blockIdx.x * 128;
    const int wr   = wv >> 1, wc = wv & 1;
    const int fr   = lane & 15;
    const int fq   = lane >> 4;
    const int srow = lane >> 2;
    const int ske  = (lane & 3) * 8;

    f32x4 acc[4][4] = {};

    for (int k0 = 0; k0 < K; k0 += 32) {
#pragma unroll
        for (int q = 0; q < 2; ++q) {
            const int c2 = wv * 2 + q;
            gload16(A + (size_t)(bm + c2 * 16 + srow) * K + k0 + ske,
                    (char*)sA + c2 * 1024);
            gload16(W + (size_t)(bn + c2 * 16 + srow) * K + k0 + ske,
                    (char*)sB + c2 * 1024);
        }
        __syncthreads();

        short8 af[4], bf[4];
#pragma unroll
        for (int mi = 0; mi < 4; ++mi)
            af[mi] = *(const short8*)&sA[(wr * 64 + mi * 16 + fr) * 32 + fq * 8];
#pragma unroll
        for (int ni = 0; ni < 4; ++ni)
            bf[ni] = *(const short8*)&sB[(wc * 64 + ni * 16 + fr) * 32 + fq * 8];
#pragma unroll
        for (int mi = 0; mi < 4; ++mi)
#pragma unroll
            for (int ni = 0; ni < 4; ++ni)
                acc[mi][ni] = mm16(af[mi], bf[ni], acc[mi][ni]);
        __syncthreads();
    }

    float* Cb; const float* bb; int coff, ldc;
    if (bn < Nsplit) { Cb = C0; bb = bias0; coff = 0;      ldc = ld0; }
    else             { Cb = C1; bb = bias1; coff = Nsplit; ldc = ld1; }

#pragma unroll
    for (int mi = 0; mi < 4; ++mi)
#pragma unroll
        for (int ni = 0; ni < 4; ++ni) {
            const int col = bn + wc * 64 + ni * 16 + fr - coff;
            const float bv = bb[col];
#pragma unroll
            for (int r = 0; r < 4; ++r) {
                const int row = bm + wr * 64 + mi * 16 + fq * 4 + r;
                Cb[(size_t)row * ldc + col] = acc[mi][ni][r] + bv;
            }
        }
}

// ---------------------------------------------------------------------------
// Small GEMM for a_angle.
// ---------------------------------------------------------------------------
__global__ __launch_bounds__(256) void gemm_a_kernel(
    const float* __restrict__ x, const float* __restrict__ wa,
    const float* __restrict__ ba, float* __restrict__ out)
{
    const int w    = threadIdx.x >> 6;
    const int lane = threadIdx.x & 63;
    const int oidx = blockIdx.x * 4 + w;
    const int r = oidx >> 3, h = oidx & 7;
    const float* xr = x + (size_t)r * DIM_;
    const float* wr = wa + (size_t)h * DIM_;
    float p = 0.f;
    for (int k = lane; k < DIM_; k += 64)
        p = fmaf(xr[k], wr[k], p);
#pragma unroll
    for (int off = 32; off; off >>= 1)
        p += __shfl_down(p, off);
    if (lane == 0) out[oidx] = p + ba[h];
}

// ---------------------------------------------------------------------------
// Phase kernel: in-place qk -> (qp, kp).
// ---------------------------------------------------------------------------
__global__ __launch_bounds__(256) void phase_kernel(
    float* __restrict__ qk, const float* __restrict__ p_angle)
{
    const int idx = blockIdx.x * 256 + threadIdx.x;
    const int i = idx & 63;
    const int h = (idx >> 6) & 7;
    const int l = (idx >> 9) & (L_ - 1);
    const float th = p_angle[h * DQK_ + i];
    float s, c;
    __sincosf(th * (float)l, &s, &c);
    float4 qv = *(float4*)(qk + (size_t)idx * 4);
    float4 o;
    o.x = qv.x * c - qv.y * s;
    o.y = qv.x * s + qv.y * c;
    o.z = qv.z * c + qv.w * s;
    o.w = qv.w * c - qv.z * s;
    *(float4*)(qk + (size_t)idx * 4) = o;
}

// ---------------------------------------------------------------------------
// chunkA_mfma: one block per (b,h,chunk), 256 threads / 4 waves.
// bf16 LDS planes + mfma_16x16x32 for P = Q~K~^T (masked), H = P V, Z = K~^T V.
// ---------------------------------------------------------------------------
__global__ __launch_bounds__(256) void chunkA_mfma(
    const float* __restrict__ qpkp, const float* __restrict__ vbuf,
    const float* __restrict__ a_ang, const float* __restrict__ p_angle,
    float* __restrict__ h_pre, float* __restrict__ Zloc,
    float* __restrict__ Gbuf, float* __restrict__ Wbuf)
{
    const int blk = blockIdx.x;
    const int c  = blk & 7;
    const int bh = blk >> 3;
    const int b = bh >> 3, h = bh & 7;
    const int t = threadIdx.x;
    const int l0 = c * 64;

    __shared__ unsigned short pQr[4096], pQi[4096];   // later reused as Pr, Pi
    __shared__ unsigned short pKr[4096], pKi[4096];   // [m][i]
    __shared__ unsigned short pKtr[4096], pKti[4096]; // [i][m]
    __shared__ unsigned short pVtr[4096], pVti[4096]; // [v][m]
    __shared__ float sW[64][4];

    // --- lambda cumprod scan (wave 0) ---
    if (t < 64) {
        const float th0 = p_angle[h * DQK_];
        const float a = a_ang[((size_t)(b * L_) + l0 + t) * H_ + h];
        float sa, ca; __sincosf(a * th0, &sa, &ca);
        const float em = expf(-th0), ep = expf(th0);
        float lr = em * ca, li = em * sa;      // lambda
        float ir = ep * ca, ii = -ep * sa;     // 1/lambda
#pragma unroll
        for (int off = 1; off < 64; off <<= 1) {
            const float plr = __shfl_up(lr, off);
            const float pli = __shfl_up(li, off);
            const float pir = __shfl_up(ir, off);
            const float pii = __shfl_up(ii, off);
            if (t >= off) {
                float nr = lr * plr - li * pli;
                float ni = lr * pli + li * plr;
                lr = nr; li = ni;
                nr = ir * pir - ii * pii;
                ni = ir * pii + ii * pir;
                ir = nr; ii = ni;
            }
        }
        sW[t][0] = lr; sW[t][1] = li; sW[t][2] = ir; sW[t][3] = ii;
        Wbuf[((size_t)bh * L_ + l0 + t) * 2 + 0] = lr;
        Wbuf[((size_t)bh * L_ + l0 + t) * 2 + 1] = li;
        if (t == 63) {
            Gbuf[(bh * 8 + c) * 2 + 0] = lr;
            Gbuf[(bh * 8 + c) * 2 + 1] = li;
        }
    }
    __syncthreads();

    // --- load planes: thread t owns (row = t>>2, 16-col segment cs = t&3) ---
    const int row = t >> 2, cs = t & 3;
    {
        const float wr = sW[row][0], wi = sW[row][1];
        const float xr = sW[row][2], xi = sW[row][3];
        unsigned short qr16[16], qi16[16], kr16[16], ki16[16];
        const float4* qg = (const float4*)(qpkp +
            (((size_t)(b * L_ + l0 + row) * H_ + h) * 64 + cs * 16) * 4);
#pragma unroll
        for (int j = 0; j < 16; ++j) {
            const float4 q = qg[j];
            qr16[j] = f2bf(q.x * wr - q.y * wi);
            qi16[j] = f2bf(q.x * wi + q.y * wr);
            const float kr = q.z * xr - q.w * xi;
            const float ki = q.z * xi + q.w * xr;
            kr16[j] = f2bf(kr); ki16[j] = f2bf(ki);
            const int i = cs * 16 + j;      // transposed K writes [i][m=row]
            const int ob = swoff(i, 2 * row);
            *(unsigned short*)((char*)pKtr + ob) = kr16[j];
            *(unsigned short*)((char*)pKti + ob) = ki16[j];
        }
        const int kb0 = 32 * cs;
        short8 s0, s1;
#pragma unroll
        for (int j = 0; j < 8; ++j) { s0[j] = (short)qr16[j]; s1[j] = (short)qr16[8 + j]; }
        *(short8*)((char*)pQr + swoff(row, kb0))      = s0;
        *(short8*)((char*)pQr + swoff(row, kb0 + 16)) = s1;
#pragma unroll
        for (int j = 0; j < 8; ++j) { s0[j] = (short)qi16[j]; s1[j] = (short)qi16[8 + j]; }
        *(short8*)((char*)pQi + swoff(row, kb0))      = s0;
        *(short8*)((char*)pQi + swoff(row, kb0 + 16)) = s1;
#pragma unroll
        for (int j = 0; j < 8; ++j) { s0[j] = (short)kr16[j]; s1[j] = (short)kr16[8 + j]; }
        *(short8*)((char*)pKr + swoff(row, kb0))      = s0;
        *(short8*)((char*)pKr + swoff(row, kb0 + 16)) = s1;
#pragma unroll
        for (int j = 0; j < 8; ++j) { s0[j] = (short)ki16[j]; s1[j] = (short)ki16[8 + j]; }
        *(short8*)((char*)pKi + swoff(row, kb0))      = s0;
        *(short8*)((char*)pKi + swoff(row, kb0 + 16)) = s1;

        const float2* vg = (const float2*)(vbuf +
            (((size_t)(b * L_ + l0 + row) * H_ + h) * 64 + cs * 16) * 2);
#pragma unroll
        for (int j = 0; j < 16; ++j) {
            const float2 vv = vg[j];
            const int v = cs * 16 + j;      // transposed V writes [v][m=row]
            const int ob = swoff(v, 2 * row);
            *(unsigned short*)((char*)pVtr + ob) = f2bf(vv.x);
            *(unsigned short*)((char*)pVti + ob) = f2bf(vv.y);
        }
    }
    __syncthreads();

    // --- P = Q~ K~^T (wave w owns l-strip w) ---
    const int w = t >> 6, lane = t & 63;
    const int fr = lane & 15, fq = lane >> 4;
    short8 aQr0 = frag(pQr, w, 0, lane), aQr1 = frag(pQr, w, 1, lane);
    short8 aQi0 = frag(pQi, w, 0, lane), aQi1 = frag(pQi, w, 1, lane);
    f32x4 Pr[4], Pi[4];
#pragma unroll
    for (int tm = 0; tm < 4; ++tm) {
        short8 bKr0 = frag(pKr, tm, 0, lane), bKr1 = frag(pKr, tm, 1, lane);
        short8 bKi0 = frag(pKi, tm, 0, lane), bKi1 = frag(pKi, tm, 1, lane);
        f32x4 tmp = {};
        tmp = mm16(aQi0, bKi0, tmp); tmp = mm16(aQi1, bKi1, tmp);
        tmp = -tmp;
        tmp = mm16(aQr0, bKr0, tmp); tmp = mm16(aQr1, bKr1, tmp);
        Pr[tm] = tmp;
        f32x4 t2 = {};
        t2 = mm16(aQr0, bKi0, t2); t2 = mm16(aQr1, bKi1, t2);
        t2 = mm16(aQi0, bKr0, t2); t2 = mm16(aQi1, bKr1, t2);
        Pi[tm] = t2;
    }
    // mask (keep m<=l) and write P into pQr/pQi (wave-own rows only: no barrier)
#pragma unroll
    for (int tm = 0; tm < 4; ++tm) {
        const int m = tm * 16 + fr;
#pragma unroll
        for (int r = 0; r < 4; ++r) {
            const int l = w * 16 + fq * 4 + r;
            const int ob = swoff(l, 2 * m);
            const float prv = (m <= l) ? Pr[tm][r] : 0.f;
            const float piv = (m <= l) ? Pi[tm][r] : 0.f;
            *(unsigned short*)((char*)pQr + ob) = f2bf(prv);
            *(unsigned short*)((char*)pQi + ob) = f2bf(piv);
        }
    }

    // --- H = P V and Z = K~^T V (shared V fragments) ---
    short8 aPr0 = frag(pQr, w, 0, lane), aPr1 = frag(pQr, w, 1, lane);
    short8 aPi0 = frag(pQi, w, 0, lane), aPi1 = frag(pQi, w, 1, lane);
    short8 aKt_r0 = frag(pKtr, w, 0, lane), aKt_r1 = frag(pKtr, w, 1, lane);
    short8 aKt_i0 = frag(pKti, w, 0, lane), aKt_i1 = frag(pKti, w, 1, lane);
    const float Gr = sW[63][0], Gi = sW[63][1];
#pragma unroll
    for (int tv = 0; tv < 4; ++tv) {
        short8 bVr0 = frag(pVtr, tv, 0, lane), bVr1 = frag(pVtr, tv, 1, lane);
        short8 bVi0 = frag(pVti, tv, 0, lane), bVi1 = frag(pVti, tv, 1, lane);
        f32x4 hr = {};
        hr = mm16(aPi0, bVi0, hr); hr = mm16(aPi1, bVi1, hr);
        hr = -hr;
        hr = mm16(aPr0, bVr0, hr); hr = mm16(aPr1, bVr1, hr);
        f32x4 hi = {};
        hi = mm16(aPr0, bVi0, hi); hi = mm16(aPr1, bVi1, hi);
        hi = mm16(aPi0, bVr0, hi); hi = mm16(aPi1, bVr1, hi);
        f32x4 zr = {};
        zr = mm16(aKt_i0, bVi0, zr); zr = mm16(aKt_i1, bVi1, zr);
        zr = -zr;
        zr = mm16(aKt_r0, bVr0, zr); zr = mm16(aKt_r1, bVr1, zr);
        f32x4 zi = {};
        zi = mm16(aKt_r0, bVi0, zi); zi = mm16(aKt_r1, bVi1, zi);
        zi = mm16(aKt_i0, bVr0, zi); zi = mm16(aKt_i1, bVr1, zi);
#pragma unroll
        for (int r = 0; r < 4; ++r) {
            const int lrow = w * 16 + fq * 4 + r;    // l for H, i for Z
            const int v = tv * 16 + fr;
            *(float2*)(h_pre + (((size_t)(b * L_ + l0 + lrow) * H_ + h) * 64 + v) * 2)
                = make_float2(hr[r], hi[r]);
            float* zp = Zloc + (((size_t)(bh * 8 + c) * 4096) + lrow * 64 + v) * 2;
            zp[0] = Gr * zr[r] - Gi * zi[r];
            zp[1] = Gr * zi[r] + Gi * zr[r];
        }
    }
}

// ---------------------------------------------------------------------------
// scanB: sequential over 8 chunks, parallel over entries. In-place Zloc->Zin.
// Writes hid_next directly to d_out in the layout out_size dictates.
// ---------------------------------------------------------------------------
__global__ __launch_bounds__(512) void scanB(
    float* __restrict__ Zbuf, const float* __restrict__ Gbuf,
    const float* __restrict__ hidden, const float* __restrict__ p_angle,
    float* __restrict__ hid_out, int real_only)
{
    const int bid = blockIdx.x;
    const int bh = bid >> 3, part = bid & 7;
    const int h = bh & 7;
    const int e = part * 512 + threadIdx.x;
    const int i = e >> 6;
    const float th = p_angle[h * 64 + i];
    float s, c; __sincosf(th, &s, &c);
    const float2 h0 = *(const float2*)(hidden + ((size_t)bh * 4096 + e) * 2);
    float zr = h0.x * c - h0.y * s;
    float zi = h0.x * s + h0.y * c;
#pragma unroll
    for (int ch = 0; ch < 8; ++ch) {
        float* zp = Zbuf + ((size_t)(bh * 8 + ch) * 4096 + e) * 2;
        const float zlr = zp[0], zli = zp[1];
        zp[0] = zr; zp[1] = zi;
        const float gr = Gbuf[(bh * 8 + ch) * 2], gi = Gbuf[(bh * 8 + ch) * 2 + 1];
        const float nr = gr * zr - gi * zi + zlr;
        const float ni = gr * zi + gi * zr + zli;
        zr = nr; zi = ni;
    }
    float s2, c2; __sincosf(th * (float)(L_ - 1), &s2, &c2);
    const float outr = zr * c2 - zi * s2;
    const float outi = zr * s2 + zi * c2;
    if (real_only) {
        hid_out[(size_t)bh * 4096 + e] = outr;
    } else {
        hid_out[((size_t)bh * 4096 + e) * 2 + 0] = outr;
        hid_out[((size_t)bh * 4096 + e) * 2 + 1] = outi;
    }
}

// ---------------------------------------------------------------------------
// chunkC_mfma: h_pre += Q~ . Zin   (one block per (b,h,chunk), 256 threads)
// ---------------------------------------------------------------------------
__global__ __launch_bounds__(256) void chunkC_mfma(
    const float* __restrict__ qpkp, const float* __restrict__ Wbuf,
    const float* __restrict__ Zin, float* __restrict__ h_pre)
{
    const int blk = blockIdx.x;
    const int c = blk & 7, bh = blk >> 3;
    const int b = bh >> 3, h = bh & 7;
    const int t = threadIdx.x;
    const int l0 = c * 64;

    __shared__ unsigned short pQr[4096], pQi[4096];   // [l][i]
    __shared__ unsigned short pZtr[4096], pZti[4096]; // [v][i]

    const int row = t >> 2, cs = t & 3;
    {
        const float wr = Wbuf[((size_t)bh * L_ + l0 + row) * 2];
        const float wi = Wbuf[((size_t)bh * L_ + l0 + row) * 2 + 1];
        unsigned short qr16[16], qi16[16];
        const float4* qg = (const float4*)(qpkp +
            (((size_t)(b * L_ + l0 + row) * H_ + h) * 64 + cs * 16) * 4);
#pragma unroll
        for (int j = 0; j < 16; ++j) {
            const float4 q = qg[j];
            qr16[j] = f2bf(q.x * wr - q.y * wi);
            qi16[j] = f2bf(q.x * wi + q.y * wr);
        }
        const int kb0 = 32 * cs;
        short8 s0, s1;
#pragma unroll
        for (int j = 0; j < 8; ++j) { s0[j] = (short)qr16[j]; s1[j] = (short)qr16[8 + j]; }
        *(short8*)((char*)pQr + swoff(row, kb0))      = s0;
        *(short8*)((char*)pQr + swoff(row, kb0 + 16)) = s1;
#pragma unroll
        for (int j = 0; j < 8; ++j) { s0[j] = (short)qi16[j]; s1[j] = (short)qi16[8 + j]; }
        *(short8*)((char*)pQi + swoff(row, kb0))      = s0;
        *(short8*)((char*)pQi + swoff(row, kb0 + 16)) = s1;

        // Zin row i=row, v-seg: write transposed [v][i]
        const float2* zg = (const float2*)(Zin +
            ((size_t)(bh * 8 + c) * 4096 + row * 64 + cs * 16) * 2);
#pragma unroll
        for (int j = 0; j < 16; ++j) {
            const float2 z = zg[j];
            const int v = cs * 16 + j;
            const int ob = swoff(v, 2 * row);
            *(unsigned short*)((char*)pZtr + ob) = f2bf(z.x);
            *(unsigned short*)((char*)pZti + ob) = f2bf(z.y);
        }
    }
    __syncthreads();

    const int w = t >> 6, lane = t & 63;
    const int fr = lane & 15, fq = lane >> 4;
    short8 aQr0 = frag(pQr, w, 0, lane), aQr1 = frag(pQr, w, 1, lane);
    short8 aQi0 = frag(pQi, w, 0, lane), aQi1 = frag(pQi, w, 1, lane);
#pragma unroll
    for (int tv = 0; tv < 4; ++tv) {
        short8 bZr0 = frag(pZtr, tv, 0, lane), bZr1 = frag(pZtr, tv, 1, lane);
        short8 bZi0 = frag(pZti, tv, 0, lane), bZi1 = frag(pZti, tv, 1, lane);
        f32x4 hr = {};
        hr = mm16(aQi0, bZi0, hr); hr = mm16(aQi1, bZi1, hr);
        hr = -hr;
        hr = mm16(aQr0, bZr0, hr); hr = mm16(aQr1, bZr1, hr);
        f32x4 hi = {};
        hi = mm16(aQr0, bZi0, hi); hi = mm16(aQr1, bZi1, hi);
        hi = mm16(aQi0, bZr0, hi); hi = mm16(aQi1, bZr1, hi);
#pragma unroll
        for (int r = 0; r < 4; ++r) {
            const int l = w * 16 + fq * 4 + r;
            const int v = tv * 16 + fr;
            float2* hp = (float2*)(h_pre +
                (((size_t)(b * L_ + l0 + l) * H_ + h) * 64 + v) * 2);
            const float2 old = *hp;
            *hp = make_float2(old.x + hr[r], old.y + hi[r]);
        }
    }
}

// ---------------------------------------------------------------------------
// GroupNorm + SiLU gate -> act (bf16) [M_, 1024]
// ---------------------------------------------------------------------------
__global__ __launch_bounds__(256) void gn_silu_kernel(
    const float* __restrict__ h_pre, const float* __restrict__ g,
    const float* __restrict__ gn_w, const float* __restrict__ gn_b,
    unsigned short* __restrict__ act)
{
    const int row = blockIdx.x;
    const int t = threadIdx.x;
    const int h = t >> 5, lane = t & 31;
    const float* hp = h_pre + ((size_t)row * H_ + h) * (DV_ * 2);
    float4 vals = *(const float4*)(hp + lane * 4);
    float sum = vals.x + vals.y + vals.z + vals.w;
    float ss  = vals.x * vals.x + vals.y * vals.y + vals.z * vals.z + vals.w * vals.w;
#pragma unroll
    for (int off = 16; off; off >>= 1) {
        sum += __shfl_xor(sum, off, 32);
        ss  += __shfl_xor(ss,  off, 32);
    }
    const float mean = sum * (1.f / 128.f);
    const float var  = ss * (1.f / 128.f) - mean * mean;
    const float scl  = rsqrtf(var + EPS_) * gn_w[h];
    const float sft  = gn_b[h];

    const float* gp = g + (size_t)row * (H_ * DV_ * 2) + h * (DV_ * 2) + lane * 4;
    float4 gv = *(const float4*)gp;
    float o0, o1, o2, o3;
    {
        float hn = (vals.x - mean) * scl + sft;
        o0 = hn * gv.x / (1.f + expf(-gv.x));
        hn = (vals.y - mean) * scl + sft;
        o1 = hn * gv.y / (1.f + expf(-gv.y));
        hn = (vals.z - mean) * scl + sft;
        o2 = hn * gv.z / (1.f + expf(-gv.z));
        hn = (vals.w - mean) * scl + sft;
        o3 = hn * gv.w / (1.f + expf(-gv.w));
    }
    ushort4 ov;
    ov.x = f2bf(o0); ov.y = f2bf(o1); ov.z = f2bf(o2); ov.w = f2bf(o3);
    *(ushort4*)(act + (size_t)row * (H_ * DV_ * 2) + h * (DV_ * 2) + lane * 4) = ov;
}

// ---------------------------------------------------------------------------
// Launch
// ---------------------------------------------------------------------------
extern "C" void kernel_launch(void* const* d_in, const int* in_sizes, int n_in,
                              void* d_out, int out_size, void* d_ws, size_t ws_size,
                              hipStream_t stream)
{
    (void)in_sizes; (void)n_in; (void)ws_size;
    const float* x       = (const float*)d_in[0];
    const float* hidden  = (const float*)d_in[1];
    const float* w_qk    = (const float*)d_in[2];
    const float* b_qk    = (const float*)d_in[3];
    const float* w_v     = (const float*)d_in[4];
    const float* b_v     = (const float*)d_in[5];
    const float* w_g     = (const float*)d_in[6];
    const float* b_g     = (const float*)d_in[7];
    const float* w_a     = (const float*)d_in[8];
    const float* b_a     = (const float*)d_in[9];
    const float* w_y     = (const float*)d_in[10];
    const float* b_y     = (const float*)d_in[11];
    const float* gn_w    = (const float*)d_in[12];
    const float* gn_b    = (const float*)d_in[13];
    const float* p_angle = (const float*)d_in[14];

    float* y_out   = (float*)d_out;
    float* hid_out = (float*)d_out + (size_t)M_ * DIM_;
    const int hid_elems = out_size - M_ * DIM_;
    const int real_only = (hid_elems == B_ * H_ * DQK_ * DV_) ? 1 : 0;

    float* ws = (float*)d_ws;
    float* buf_qk  = ws;                                   // 4,194,304 floats
    float* buf_v   = buf_qk  + (size_t)M_ * H_ * DQK_ * 4; // 2,097,152
    float* buf_g   = buf_v   + (size_t)M_ * H_ * DV_ * 2;  // 2,097,152
    float* buf_a   = buf_g   + (size_t)M_ * H_ * DV_ * 2;  // 16,384
    float* buf_W   = buf_a   + (size_t)M_ * H_;            // 32,768
    float* buf_G   = buf_W   + 32 * L_ * 2;                // 512
    float* buf_Z   = buf_G   + 512;                        // 2,097,152
    float* buf_h   = buf_Z   + (size_t)32 * 8 * 4096 * 2;  // 2,097,152
    float* buf_wyb = buf_h   + (size_t)M_ * H_ * DV_ * 2 + 262144;  // 524,288

    // bf16 aliases (lifetimes disjoint from the aliased fp32 buffers)
    unsigned short* wqkb = (unsigned short*)buf_Z;
    unsigned short* wvb  = (unsigned short*)(buf_Z + 1048576);
    unsigned short* wgb  = (unsigned short*)(buf_Z + 1572864);
    unsigned short* xb   = (unsigned short*)buf_h;
    unsigned short* wyb  = (unsigned short*)buf_wyb;
    unsigned short* actb = (unsigned short*)buf_qk;

    cast_all<<<7168, 256, 0, stream>>>(x, w_qk, w_v, w_g, w_y,
                                       xb, wqkb, wvb, wgb, wyb);

    gemm_mfma<<<dim3(16, 16), 256, 0, stream>>>(
        xb, wqkb, b_qk, b_qk, buf_qk, buf_qk, 2048, 2048, 2048, M_, 2048, DIM_);
    gemm_mfma<<<dim3(16, 16), 256, 0, stream>>>(
        xb, wvb, b_v, b_g, buf_v, buf_g, 1024, 1024, 1024, M_, 2048, DIM_);

    gemm_a_kernel<<<(M_*H_)/4, 256, 0, stream>>>(x, w_a, b_a, buf_a);
    phase_kernel<<<(M_*H_*DQK_)/256, 256, 0, stream>>>(buf_qk, p_angle);

    chunkA_mfma<<<B_*H_*8, 256, 0, stream>>>(
        buf_qk, buf_v, buf_a, p_angle, buf_h, buf_Z, buf_G, buf_W);
    scanB<<<B_*H_*8, 512, 0, stream>>>(
        buf_Z, buf_G, hidden, p_angle, hid_out, real_only);
    chunkC_mfma<<<B_*H_*8, 256, 0, stream>>>(
        buf_qk, buf_W, buf_Z, buf_h);

    gn_silu_kernel<<<M_, 256, 0, stream>>>(buf_h, buf_g, gn_w, gn_b, actb);

    gemm_mfma<<<dim3(8, 16), 256, 0, stream>>>(
        actb, wyb, b_y, b_y, y_out, y_out, 1024, 1024, 1024, M_, 1024, DIM_);
}